// Round 1
// baseline (645.540 us; speedup 1.0000x reference)
//
#include <hip/hip_runtime.h>

// Problem constants (fixed by the reference):
//   x        [B=4096, D=16384] fp32
//   hashProj [D=16384, E=1024] fp32, exactly one nonzero (+-1) per row
//   out      [B=4096, E=1024]  fp32 = x @ hashProj
#define DIM_D 16384
#define DIM_E 1024
#define DIM_B 4096
#define ROWS_PER_BLOCK 4

// Kernel 1: recover (bucket index, sign) per input feature from the dense
// hash projection. One wave (64 lanes) scans one row (1024 floats) with
// fully coalesced float4 loads; exactly one lane sees the nonzero and
// writes the result directly (no reduction needed).
__global__ __launch_bounds__(256) void hash_extract_kernel(
    const float* __restrict__ hashProj,
    int* __restrict__ idx, float* __restrict__ sgn) {
  const int wave = threadIdx.x >> 6;
  const int lane = threadIdx.x & 63;
  const int row = blockIdx.x * 4 + wave;   // 4096 blocks x 4 waves = 16384 rows
  const float4* rp = (const float4*)(hashProj + (size_t)row * DIM_E);
#pragma unroll
  for (int k = 0; k < 4; ++k) {
    const int p = lane + 64 * k;           // float4 position within row
    float4 v = rp[p];
    const int base = p * 4;
    if (v.x != 0.f) { idx[row] = base + 0; sgn[row] = v.x; }
    if (v.y != 0.f) { idx[row] = base + 1; sgn[row] = v.y; }
    if (v.z != 0.f) { idx[row] = base + 2; sgn[row] = v.z; }
    if (v.w != 0.f) { idx[row] = base + 3; sgn[row] = v.w; }
  }
}

// Kernel 2: scatter-add. Each block owns ROWS_PER_BLOCK batch rows and an
// LDS fp32 accumulator of E buckets per row. Coalesced float4 reads of x;
// ds_add_f32 atomics into LDS (random buckets -> rare conflicts); coalesced
// float4 writeback of the finished rows.
__global__ __launch_bounds__(256) void hash_scatter_kernel(
    const float* __restrict__ x,
    const int* __restrict__ idx, const float* __restrict__ sgn,
    float* __restrict__ out) {
  __shared__ float acc[ROWS_PER_BLOCK][DIM_E];
  const int t = threadIdx.x;

  float* accf = &acc[0][0];
  for (int i = t; i < ROWS_PER_BLOCK * DIM_E; i += 256) accf[i] = 0.f;
  __syncthreads();

  const int b0 = blockIdx.x * ROWS_PER_BLOCK;
  const int4* idx4 = (const int4*)idx;
  const float4* sgn4 = (const float4*)sgn;

  for (int c = 0; c < DIM_D / 4 / 256; ++c) {  // 16 chunks
    const int j4 = c * 256 + t;                // float4 index within a row
    const int4 id = idx4[j4];
    const float4 sg = sgn4[j4];
#pragma unroll
    for (int r = 0; r < ROWS_PER_BLOCK; ++r) {
      const float4 xv = ((const float4*)(x + (size_t)(b0 + r) * DIM_D))[j4];
      atomicAdd(&acc[r][id.x], sg.x * xv.x);
      atomicAdd(&acc[r][id.y], sg.y * xv.y);
      atomicAdd(&acc[r][id.z], sg.z * xv.z);
      atomicAdd(&acc[r][id.w], sg.w * xv.w);
    }
  }
  __syncthreads();

#pragma unroll
  for (int r = 0; r < ROWS_PER_BLOCK; ++r) {
    float4* op = (float4*)(out + (size_t)(b0 + r) * DIM_E);
    const float4* ap = (const float4*)&acc[r][0];
    // E/4 = 256 float4s, exactly one per thread
    op[t] = ap[t];
  }
}

extern "C" void kernel_launch(void* const* d_in, const int* in_sizes, int n_in,
                              void* d_out, int out_size, void* d_ws, size_t ws_size,
                              hipStream_t stream) {
  const float* x = (const float*)d_in[0];
  const float* hashProj = (const float*)d_in[1];
  float* out = (float*)d_out;

  // Workspace layout: idx[16384] int, sgn[16384] float  (128 KiB total)
  int* idx = (int*)d_ws;
  float* sgn = (float*)((char*)d_ws + DIM_D * sizeof(int));

  hash_extract_kernel<<<DIM_D / 4, 256, 0, stream>>>(hashProj, idx, sgn);
  hash_scatter_kernel<<<DIM_B / ROWS_PER_BLOCK, 256, 0, stream>>>(x, idx, sgn, out);
}

// Round 2
// 490.919 us; speedup vs baseline: 1.3150x; 1.3150x over previous
//
#include <hip/hip_runtime.h>

// Problem constants (fixed by the reference):
//   x        [B=4096, D=16384] fp32
//   hashProj [D=16384, E=1024] fp32, exactly one nonzero (+-1) per row
//   out      [B=4096, E=1024]  fp32 = x @ hashProj
#define DIM_D 16384
#define DIM_E 1024
#define DIM_B 4096

// ---------------------------------------------------------------------------
// Kernel 1: recover (bucket index, sign) per feature from the dense hash
// projection AND histogram bucket sizes. One wave scans one row (1024 floats)
// with coalesced float4 loads; exactly one lane sees the nonzero.
// ---------------------------------------------------------------------------
__global__ __launch_bounds__(256) void hash_extract_kernel(
    const float* __restrict__ hashProj,
    int* __restrict__ idx, float* __restrict__ sgn,
    int* __restrict__ counts) {
  const int wave = threadIdx.x >> 6;
  const int lane = threadIdx.x & 63;
  const int row = blockIdx.x * 4 + wave;   // 4096 blocks x 4 waves = 16384 rows
  const float4* rp = (const float4*)(hashProj + (size_t)row * DIM_E);
  int found_e = -1;
  float found_s = 0.f;
#pragma unroll
  for (int k = 0; k < 4; ++k) {
    const int p = lane + 64 * k;           // float4 position within row
    float4 v = rp[p];
    const int base = p * 4;
    if (v.x != 0.f) { found_e = base + 0; found_s = v.x; }
    if (v.y != 0.f) { found_e = base + 1; found_s = v.y; }
    if (v.z != 0.f) { found_e = base + 2; found_s = v.z; }
    if (v.w != 0.f) { found_e = base + 3; found_s = v.w; }
  }
  if (found_e >= 0) {
    idx[row] = found_e;
    sgn[row] = found_s;
    atomicAdd(&counts[found_e], 1);        // int atomic: native, cheap
  }
}

// ---------------------------------------------------------------------------
// Kernel 2: exclusive prefix sum over the 1024 bucket counts (one block).
// Produces rowPtr[1025] and a cursor copy for the fill pass.
// ---------------------------------------------------------------------------
__global__ __launch_bounds__(1024) void hash_scan_kernel(
    const int* __restrict__ counts,
    int* __restrict__ rowPtr, int* __restrict__ cursor) {
  __shared__ int tmp[DIM_E];
  const int t = threadIdx.x;
  const int v = counts[t];
  tmp[t] = v;
  __syncthreads();
  for (int off = 1; off < DIM_E; off <<= 1) {
    int add = (t >= off) ? tmp[t - off] : 0;
    __syncthreads();
    tmp[t] += add;
    __syncthreads();
  }
  const int excl = tmp[t] - v;             // exclusive prefix
  rowPtr[t] = excl;
  cursor[t] = excl;
  if (t == DIM_E - 1) rowPtr[DIM_E] = tmp[t];
}

// ---------------------------------------------------------------------------
// Kernel 3: fill CSR entries, bucket-sorted. entry = (j << 1) | (sign < 0).
// ---------------------------------------------------------------------------
__global__ __launch_bounds__(256) void hash_fill_kernel(
    const int* __restrict__ idx, const float* __restrict__ sgn,
    int* __restrict__ cursor, int* __restrict__ entries) {
  const int j = blockIdx.x * 256 + threadIdx.x;
  const int e = idx[j];
  const int pos = atomicAdd(&cursor[e], 1);
  entries[pos] = (j << 1) | (sgn[j] < 0.f ? 1 : 0);
}

// ---------------------------------------------------------------------------
// Kernel 4: gather. One block per batch row. Stage x[b,:] (64 KiB) in LDS,
// then thread e sums its bucket's ~16 entries: plain ds_read + fma, no
// atomics. 64 KiB LDS -> 2 resident blocks/CU: gather of one block overlaps
// staging of the next.
// ---------------------------------------------------------------------------
__global__ __launch_bounds__(1024) void hash_gather_kernel(
    const float* __restrict__ x,
    const int* __restrict__ rowPtr, const int* __restrict__ entries,
    float* __restrict__ out) {
  __shared__ float xs[DIM_D];
  const int b = blockIdx.x;
  const float4* xp = (const float4*)(x + (size_t)b * DIM_D);
  float4* xs4 = (float4*)xs;
#pragma unroll
  for (int i = 0; i < DIM_D / 4 / 1024; ++i)     // 4 float4s per thread
    xs4[threadIdx.x + i * 1024] = xp[threadIdx.x + i * 1024];
  __syncthreads();

  const int e = threadIdx.x;                     // one bucket per thread
  const int beg = rowPtr[e];
  const int end = rowPtr[e + 1];
  float sum = 0.f;
  for (int k = beg; k < end; ++k) {
    const int ent = entries[k];                  // L1/L2-cached (64 KiB total)
    const float v = xs[ent >> 1];
    sum += (ent & 1) ? -v : v;
  }
  out[(size_t)b * DIM_E + e] = sum;
}

extern "C" void kernel_launch(void* const* d_in, const int* in_sizes, int n_in,
                              void* d_out, int out_size, void* d_ws, size_t ws_size,
                              hipStream_t stream) {
  const float* x = (const float*)d_in[0];
  const float* hashProj = (const float*)d_in[1];
  float* out = (float*)d_out;

  // Workspace layout (all 4-byte types):
  //   idx     [16384] int
  //   sgn     [16384] float
  //   counts  [1024]  int
  //   rowPtr  [1025]  int
  //   cursor  [1024]  int (padded to 1024+3 for alignment of next)
  //   entries [16384] int
  char* ws = (char*)d_ws;
  int*   idx     = (int*)ws;                 ws += DIM_D * sizeof(int);
  float* sgn     = (float*)ws;               ws += DIM_D * sizeof(float);
  int*   counts  = (int*)ws;                 ws += DIM_E * sizeof(int);
  int*   rowPtr  = (int*)ws;                 ws += (DIM_E + 4) * sizeof(int);
  int*   cursor  = (int*)ws;                 ws += DIM_E * sizeof(int);
  int*   entries = (int*)ws;

  // ws is re-poisoned to 0xAA before every timed call: zero the histogram.
  hipMemsetAsync(counts, 0, DIM_E * sizeof(int), stream);

  hash_extract_kernel<<<DIM_D / 4, 256, 0, stream>>>(hashProj, idx, sgn, counts);
  hash_scan_kernel<<<1, 1024, 0, stream>>>(counts, rowPtr, cursor);
  hash_fill_kernel<<<DIM_D / 256, 256, 0, stream>>>(idx, sgn, cursor, entries);
  hash_gather_kernel<<<DIM_B, 1024, 0, stream>>>(x, rowPtr, entries, out);
}

// Round 3
// 409.227 us; speedup vs baseline: 1.5775x; 1.1996x over previous
//
#include <hip/hip_runtime.h>

// Problem constants (fixed by the reference):
//   x        [B=4096, D=16384] fp32
//   hashProj [D=16384, E=1024] fp32, exactly one nonzero (+-1) per row
//   out      [B=4096, E=1024]  fp32 = x @ hashProj
#define DIM_D 16384
#define DIM_E 1024
#define DIM_B 4096
#define ELL_CAP 64   // max bucket size capacity; counts are ~Poisson(16), P(>64) ~ 1e-50

// ---------------------------------------------------------------------------
// Kernel 1: extract (idx, sgn) per feature row from the dense hash projection
// (one wave per row, coalesced float4 scan; exactly one lane sees +-1).
// Also: prefill ELL table with -1 (pad marker) and zero cursor+meta, so no
// separate memset / scan dispatches are needed.
// ---------------------------------------------------------------------------
__global__ __launch_bounds__(256) void hash_extract_kernel(
    const float* __restrict__ hashProj,
    int* __restrict__ idx, float* __restrict__ sgn,
    int* __restrict__ cursor /* [1024] + meta[16] right after */,
    int* __restrict__ ell) {
  const int gid = blockIdx.x * 256 + threadIdx.x;

  // Prefill ELL (64K int4 = 256 KiB) with pad marker -1.
  if (gid < (ELL_CAP / 4) * DIM_E) {
    ((int4*)ell)[gid] = make_int4(-1, -1, -1, -1);
  }
  // Zero the 1024 cursors + meta words.
  if (gid < DIM_E + 16) cursor[gid] = 0;

  const int wave = threadIdx.x >> 6;
  const int lane = threadIdx.x & 63;
  const int row = blockIdx.x * 4 + wave;   // 4096 blocks x 4 waves = 16384 rows
  const float4* rp = (const float4*)(hashProj + (size_t)row * DIM_E);
  int found_e = -1;
  float found_s = 0.f;
#pragma unroll
  for (int k = 0; k < 4; ++k) {
    const int p = lane + 64 * k;           // float4 position within row
    float4 v = rp[p];
    const int base = p * 4;
    if (v.x != 0.f) { found_e = base + 0; found_s = v.x; }
    if (v.y != 0.f) { found_e = base + 1; found_s = v.y; }
    if (v.z != 0.f) { found_e = base + 2; found_s = v.z; }
    if (v.w != 0.f) { found_e = base + 3; found_s = v.w; }
  }
  if (found_e >= 0) {
    idx[row] = found_e;
    sgn[row] = found_s;
  }
}

// ---------------------------------------------------------------------------
// Kernel 2: fill transposed ELL. Entry for slot s of bucket e lives at int
// offset (s>>2)*4*DIM_E + 4*e + (s&3), i.e. int4 g=s>>2 is ell4[g*1024+e]
// (lane-consecutive e -> coalesced int4 loads in the gather).
// meta[0] accumulates the max slot index (-> uniform trip count).
// ---------------------------------------------------------------------------
__global__ __launch_bounds__(256) void hash_fill_kernel(
    const int* __restrict__ idx,
    int* __restrict__ cursor, int* __restrict__ meta,
    int* __restrict__ ell) {
  const int j = blockIdx.x * 256 + threadIdx.x;
  const int e = idx[j];
  const int s = atomicAdd(&cursor[e], 1);
  ell[(s >> 2) * (4 * DIM_E) + 4 * e + (s & 3)] = j;
  atomicMax(&meta[0], s);
}

// ---------------------------------------------------------------------------
// Kernel 3: gather. One block (1024 threads) per batch row. Stage the row
// into LDS PRE-SIGNED (xs[j] = sgn[j]*x[b,j], coalesced float4). Then thread
// e sums its bucket via the ELL table: uniform trip count G (no divergence),
// int4 entry loads coalesced + register-prefetched, 4 independent ds_read
// chains per group. Pad entries (-1) decode to a broadcast LDS read masked
// to 0.0f -- branchless, bank-conflict-free.
// ---------------------------------------------------------------------------
__device__ __forceinline__ float ell_val(const float* xs, int q) {
  // q >= 0: xs[q]; q < 0 (pad): 0.0f. Pad address aliases to 16383
  // (same for all pad lanes -> LDS broadcast).
  float v = xs[q & (DIM_D - 1)];
  return __int_as_float(__float_as_int(v) & ~(q >> 31));
}

__global__ __launch_bounds__(1024) void hash_gather_kernel(
    const float* __restrict__ x, const float* __restrict__ sgn,
    const int* __restrict__ meta, const int* __restrict__ ell,
    float* __restrict__ out) {
  __shared__ float xs[DIM_D];
  const int t = threadIdx.x;
  const int b = blockIdx.x;
  const float4* xp = (const float4*)(x + (size_t)b * DIM_D);
  const float4* sp = (const float4*)sgn;
  float4* xs4 = (float4*)xs;
#pragma unroll
  for (int i = 0; i < DIM_D / 4 / 1024; ++i) {   // 4 float4s per thread
    const int p = t + i * 1024;
    float4 xv = xp[p];
    float4 sv = sp[p];
    xs4[p] = make_float4(xv.x * sv.x, xv.y * sv.y, xv.z * sv.z, xv.w * sv.w);
  }
  __syncthreads();

  const int G = (meta[0] + 4) >> 2;              // uniform group count
  const int4* ell4 = (const int4*)ell;
  const int e = t;
  float s0 = 0.f, s1 = 0.f, s2 = 0.f, s3 = 0.f;
  int4 q = ell4[e];                              // prefetch group 0
  for (int g = 1; g < G; ++g) {
    int4 qn = ell4[g * DIM_E + e];               // prefetch next group
    s0 += ell_val(xs, q.x);
    s1 += ell_val(xs, q.y);
    s2 += ell_val(xs, q.z);
    s3 += ell_val(xs, q.w);
    q = qn;
  }
  s0 += ell_val(xs, q.x);
  s1 += ell_val(xs, q.y);
  s2 += ell_val(xs, q.z);
  s3 += ell_val(xs, q.w);
  out[(size_t)b * DIM_E + e] = (s0 + s1) + (s2 + s3);
}

extern "C" void kernel_launch(void* const* d_in, const int* in_sizes, int n_in,
                              void* d_out, int out_size, void* d_ws, size_t ws_size,
                              hipStream_t stream) {
  const float* x = (const float*)d_in[0];
  const float* hashProj = (const float*)d_in[1];
  float* out = (float*)d_out;

  // Workspace layout (16B-aligned sections):
  //   idx    [16384] int     ( 64 KiB)
  //   sgn    [16384] float   ( 64 KiB)
  //   cursor [1024] + meta[16] int (4160 B, padded to 4224)
  //   ell    [64 * 1024] int (256 KiB)
  char* ws = (char*)d_ws;
  int*   idx    = (int*)ws;                ws += DIM_D * sizeof(int);
  float* sgn    = (float*)ws;              ws += DIM_D * sizeof(float);
  int*   cursor = (int*)ws;                ws += (DIM_E + 32) * sizeof(int);
  int*   meta   = cursor + DIM_E;
  int*   ell    = (int*)ws;

  hash_extract_kernel<<<DIM_D / 4, 256, 0, stream>>>(hashProj, idx, sgn, cursor, ell);
  hash_fill_kernel<<<DIM_D / 256, 256, 0, stream>>>(idx, cursor, meta, ell);
  hash_gather_kernel<<<DIM_B, 1024, 0, stream>>>(x, sgn, meta, ell, out);
}